// Round 3
// baseline (605.651 us; speedup 1.0000x reference)
//
#include <hip/hip_runtime.h>

// QLSTM: B=512, T=1024, IN=1, H=64.
// 8 waves per batch element (block=512). Wave w owns gate-rows [32w, 32w+32)
// (gate g = w>>1, PyTorch i,f,g,o order). Lane l computes row 32w+(l&31) over
// K-half (l>>5)*32: 32 FMAs (4 accumulator chains) + one shfl_xor(32).
// Weights: 8 float4 = 32 VGPRs per lane (small live range -> arch VGPRs).
//
// Exchange (1 barrier/step):
//  - gate activations through double-buffered act[t&1][unit][4]; epilogue
//    reads all 4 gates of its unit with a single ds_read_b128.
//  - c,h update redundant in every wave; h kept in a per-wave PRIVATE LDS
//    copy hs[w][64] (same-wave DS ordering -> no barrier for h).

#define TLEN 1024
#define HID  64

__device__ __forceinline__ float fast_sigmoid(float x) {
    return __builtin_amdgcn_rcpf(1.0f + __expf(-x));   // hw exp + hw rcp
}
__device__ __forceinline__ float fast_tanh(float x) {
    return __builtin_fmaf(2.0f, fast_sigmoid(2.0f * x), -1.0f);
}

__global__ __launch_bounds__(512, 4)
void qlstm_kernel(const float* __restrict__ x,      // [B, T, 1]
                  const float* __restrict__ W_ih,   // [256, 1]
                  const float* __restrict__ W_hh,   // [256, 64]
                  const float* __restrict__ b_ih,   // [256]
                  const float* __restrict__ b_hh,   // [256]
                  const float* __restrict__ W_lin,  // [1, 64]
                  const float* __restrict__ b_lin,  // [1]
                  float* __restrict__ out)          // [B]
{
    const int b   = blockIdx.x;
    const int tid = threadIdx.x;
    const int w   = tid >> 6;        // wave 0..7
    const int l   = tid & 63;
    const int lr  = l & 31;          // row-within-wave
    const int kh  = l >> 5;          // K-half (0/1)
    const int g   = w >> 1;          // gate 0..3
    const int row = w * 32 + lr;     // global gate-row 0..255
    const int k0  = kh * 32;

    __shared__ __align__(16) float xs[TLEN];           // 4 KB
    __shared__ __align__(16) float hs[8][HID];         // per-wave private h
    __shared__ __align__(16) float act[2][HID][4];     // [parity][unit][gate]

    // Stage x row: 1024 floats, one float2 per thread.
    ((float2*)xs)[tid] = ((const float2*)(x + (size_t)b * TLEN))[tid];

    // This lane's 32 weights: W_hh[row][k0 .. k0+31].
    const float4* Wr = (const float4*)(W_hh + (size_t)row * HID + k0);
    float4 wq[8];
    #pragma unroll
    for (int q = 0; q < 8; ++q) wq[q] = Wr[q];

    const float u    = W_ih[row];                  // IN == 1
    const float bias = b_ih[row] + b_hh[row];
    const float wlin = W_lin[l];

    float c = 0.0f, h = 0.0f;
    hs[w][l] = 0.0f;
    __syncthreads();   // xs + hs ready

    for (int t = 0; t < TLEN; ++t) {
        const int p = t & 1;
        const float xt = xs[t];                    // same-address broadcast
        const float base = __builtin_fmaf(xt, u, bias);

        // Partial dot over this lane's K-half, 4 accumulator chains.
        float acc0 = (kh == 0) ? base : 0.0f;      // x/bias term added once
        float acc1 = 0.0f, acc2 = 0.0f, acc3 = 0.0f;
        #pragma unroll
        for (int q = 0; q < 8; q += 4) {
            const float4 ha = *(const float4*)&hs[w][k0 + 4 * (q + 0)];
            const float4 hb = *(const float4*)&hs[w][k0 + 4 * (q + 1)];
            const float4 hc = *(const float4*)&hs[w][k0 + 4 * (q + 2)];
            const float4 hd = *(const float4*)&hs[w][k0 + 4 * (q + 3)];
            acc0 = __builtin_fmaf(ha.x, wq[q + 0].x, acc0);
            acc0 = __builtin_fmaf(ha.y, wq[q + 0].y, acc0);
            acc0 = __builtin_fmaf(ha.z, wq[q + 0].z, acc0);
            acc0 = __builtin_fmaf(ha.w, wq[q + 0].w, acc0);
            acc1 = __builtin_fmaf(hb.x, wq[q + 1].x, acc1);
            acc1 = __builtin_fmaf(hb.y, wq[q + 1].y, acc1);
            acc1 = __builtin_fmaf(hb.z, wq[q + 1].z, acc1);
            acc1 = __builtin_fmaf(hb.w, wq[q + 1].w, acc1);
            acc2 = __builtin_fmaf(hc.x, wq[q + 2].x, acc2);
            acc2 = __builtin_fmaf(hc.y, wq[q + 2].y, acc2);
            acc2 = __builtin_fmaf(hc.z, wq[q + 2].z, acc2);
            acc2 = __builtin_fmaf(hc.w, wq[q + 2].w, acc2);
            acc3 = __builtin_fmaf(hd.x, wq[q + 3].x, acc3);
            acc3 = __builtin_fmaf(hd.y, wq[q + 3].y, acc3);
            acc3 = __builtin_fmaf(hd.z, wq[q + 3].z, acc3);
            acc3 = __builtin_fmaf(hd.w, wq[q + 3].w, acc3);
        }
        float accv = (acc0 + acc1) + (acc2 + acc3);
        accv += __shfl_xor(accv, 32, 64);          // combine K-halves

        // Wave-uniform activation type; lanes <32 publish.
        const float a = (g == 2) ? fast_tanh(accv) : fast_sigmoid(accv);
        if (lr == l)  // l < 32
            act[p][(w & 1) * 32 + lr][g] = a;
        __syncthreads();                           // the ONE barrier per step

        // Redundant elementwise update in every wave (one b128 per lane).
        const float4 a4 = *(const float4*)&act[p][l][0];   // i,f,g,o
        c = __builtin_fmaf(a4.y, c, a4.x * a4.z);
        h = a4.w * fast_tanh(c);
        hs[w][l] = h;                              // private copy; no barrier
    }

    // out[b] = dot(h, W_lin) + b_lin  (wave 0 only)
    if (w == 0) {
        float v = h * wlin;
        #pragma unroll
        for (int off = 32; off > 0; off >>= 1)
            v += __shfl_down(v, off, 64);
        if (l == 0) out[b] = v + b_lin[0];
    }
}

extern "C" void kernel_launch(void* const* d_in, const int* in_sizes, int n_in,
                              void* d_out, int out_size, void* d_ws, size_t ws_size,
                              hipStream_t stream) {
    const float* x     = (const float*)d_in[0];
    const float* W_ih  = (const float*)d_in[1];
    const float* W_hh  = (const float*)d_in[2];
    const float* b_ih  = (const float*)d_in[3];
    const float* b_hh  = (const float*)d_in[4];
    const float* W_lin = (const float*)d_in[5];
    const float* b_lin = (const float*)d_in[6];
    float* out = (float*)d_out;

    const int B = out_size;  // 512
    qlstm_kernel<<<B, 512, 0, stream>>>(x, W_ih, W_hh, b_ih, b_hh, W_lin, b_lin, out);
}